// Round 2
// baseline (589.446 us; speedup 1.0000x reference)
//
#include <hip/hip_runtime.h>
#include <math.h>

#define BATCH 32
#define TLEN  4096
#define DIM   64
#define NHASH 8
#define NBUCK 64   // n_buckets
#define BSIZE 64   // bucket size

typedef __attribute__((ext_vector_type(8))) short short8;
typedef __attribute__((ext_vector_type(8))) unsigned short ushort8;
typedef __attribute__((ext_vector_type(4))) float float4v;
typedef __attribute__((ext_vector_type(4))) unsigned int uint4v;

__device__ inline unsigned short bf16_rne(float x) {
  unsigned u = __float_as_uint(x);
  u += 0x7FFFu + ((u >> 16) & 1u);
  return (unsigned short)(u >> 16);
}
__device__ inline float bf16_to_f32(unsigned short h) {
  return __uint_as_float(((unsigned)h) << 16);
}

// ---------------------------------------------------------------------------
// Prep kernel (one-time, 8 blocks): transpose + bf16-split proj (verified r9).
// ---------------------------------------------------------------------------
__global__ __launch_bounds__(256)
void prep_kernel(const float* __restrict__ proj, unsigned short* __restrict__ pjh,
                 unsigned short* __restrict__ pjl, float* __restrict__ proj_t) {
  const int r = blockIdx.x;
  const int tid = threadIdx.x;
  for (int kk = 0; kk < 16; ++kk) {
    int idx = kk * 256 + tid;        // 4096 = 64d x 64n
    int d = idx >> 6, nn = idx & 63;
    float val = proj[d * 512 + r * 64 + nn];
    unsigned short hb = bf16_rne(val);
    unsigned short lb = bf16_rne(val - bf16_to_f32(hb));
    int g = d >> 3, e = d & 7;
    int o = (nn << 6) + ((g ^ (nn & 7)) << 3) + e;
    pjh[r * 4096 + o] = hb;
    pjl[r * 4096 + o] = lb;
    proj_t[r * 4096 + nn * 64 + d] = val;
  }
}

// ---------------------------------------------------------------------------
// Per-chunk bf16 split prepass (round-10): q -> qh/ql (pre-scaled 1/8),
// k -> kh/kl, v -> vh. Memory-bound. blockIdx.y selects the array.
// ---------------------------------------------------------------------------
__global__ __launch_bounds__(256)
void convert_kernel(const float* __restrict__ q, const float* __restrict__ k,
                    const float* __restrict__ v,
                    unsigned short* __restrict__ qh, unsigned short* __restrict__ ql,
                    unsigned short* __restrict__ kh, unsigned short* __restrict__ kl,
                    unsigned short* __restrict__ vh, int b_off) {
  const size_t idx = (size_t)blockIdx.x * 256 + threadIdx.x;  // CB*T*D/8 chunks
  const int which = blockIdx.y;
  const size_t soff = ((size_t)b_off * TLEN * DIM) + idx * 8;
  const size_t doff = idx * 8;
  if (which == 0) {
    float4 a = *(const float4*)(q + soff);
    float4 b = *(const float4*)(q + soff + 4);
    float vv[8] = {a.x, a.y, a.z, a.w, b.x, b.y, b.z, b.w};
    ushort8 h8, l8;
#pragma unroll
    for (int j = 0; j < 8; ++j) {
      float s = vv[j] * 0.125f;
      unsigned short hb = bf16_rne(s);
      h8[j] = hb;
      l8[j] = bf16_rne(s - bf16_to_f32(hb));
    }
    *(ushort8*)(qh + doff) = h8;
    *(ushort8*)(ql + doff) = l8;
  } else if (which == 1) {
    float4 a = *(const float4*)(k + soff);
    float4 b = *(const float4*)(k + soff + 4);
    float vv[8] = {a.x, a.y, a.z, a.w, b.x, b.y, b.z, b.w};
    ushort8 h8, l8;
#pragma unroll
    for (int j = 0; j < 8; ++j) {
      unsigned short hb = bf16_rne(vv[j]);
      h8[j] = hb;
      l8[j] = bf16_rne(vv[j] - bf16_to_f32(hb));
    }
    *(ushort8*)(kh + doff) = h8;
    *(ushort8*)(kl + doff) = l8;
  } else {
    float4 a = *(const float4*)(v + soff);
    float4 b = *(const float4*)(v + soff + 4);
    float vv[8] = {a.x, a.y, a.z, a.w, b.x, b.y, b.z, b.w};
    ushort8 h8;
#pragma unroll
    for (int j = 0; j < 8; ++j) h8[j] = bf16_rne(vv[j]);
    *(ushort8*)(vh + doff) = h8;
  }
}

// ---------------------------------------------------------------------------
// MFMA hash kernel (verified r9, unchanged): bf16x4 MFMA dots + exact f64
// cooperative fallback inside the rigorous margin -> decisions bit-identical
// to f64 argmax.
// ---------------------------------------------------------------------------
__global__ __launch_bounds__(256, 2)
void hash_kernel(const float* __restrict__ x, const float* __restrict__ proj_t,
                 const unsigned short* __restrict__ pjh,
                 const unsigned short* __restrict__ pjl,
                 int* __restrict__ buckets) {
  __shared__ __align__(16) unsigned short pbh[64 * 64];
  __shared__ __align__(16) unsigned short pbl[64 * 64];
  __shared__ float sxs[64];

  const int tid = threadIdx.x;
  const int w = tid >> 6;
  const int l = tid & 63;
  const int l15 = l & 15;
  const int qd = l >> 4;
  const int r = blockIdx.y, b = blockIdx.z;
  const int t0 = blockIdx.x << 6;

  const unsigned short* gh = pjh + (size_t)r * 4096;
  const unsigned short* gl = pjl + (size_t)r * 4096;
#pragma unroll
  for (int it = 0; it < 2; ++it) {
    int idx = it * 256 + tid;
    *(short8*)&pbh[idx * 8] = *(const short8*)&gh[idx * 8];
    *(short8*)&pbl[idx * 8] = *(const short8*)&gl[idx * 8];
  }

  const int trow_a = t0 + w * 16 + l15;
  const float* xra = x + ((size_t)b * TLEN + trow_a) * DIM;
  short8 Ahi[2], Alo[2];
  float sxp = 0.f;
#pragma unroll
  for (int ks = 0; ks < 2; ++ks) {
    float4 x0 = *(const float4*)(xra + ks * 32 + qd * 8);
    float4 x1 = *(const float4*)(xra + ks * 32 + qd * 8 + 4);
    sxp += fabsf(x0.x) + fabsf(x0.y) + fabsf(x0.z) + fabsf(x0.w)
         + fabsf(x1.x) + fabsf(x1.y) + fabsf(x1.z) + fabsf(x1.w);
    float v[8] = {x0.x, x0.y, x0.z, x0.w, x1.x, x1.y, x1.z, x1.w};
#pragma unroll
    for (int j = 0; j < 8; ++j) {
      unsigned short hb = bf16_rne(v[j]);
      Ahi[ks][j] = (short)hb;
      Alo[ks][j] = (short)bf16_rne(v[j] - bf16_to_f32(hb));
    }
  }
  sxp += __shfl_xor(sxp, 16, 64);
  sxp += __shfl_xor(sxp, 32, 64);
  if (qd == 0) sxs[w * 16 + l15] = sxp;
  __syncthreads();

  float4v Sacc[4];
#pragma unroll
  for (int nt = 0; nt < 4; ++nt) {
    float4v z = {0.f, 0.f, 0.f, 0.f};
    Sacc[nt] = z;
#pragma unroll
    for (int ks = 0; ks < 2; ++ks) {
      int nn = nt * 16 + l15;
      int gk = ks * 4 + qd;
      int o = (nn << 6) + ((gk ^ (nn & 7)) << 3);
      short8 Bh = *(const short8*)&pbh[o];
      short8 Bl = *(const short8*)&pbl[o];
      Sacc[nt] = __builtin_amdgcn_mfma_f32_16x16x32_bf16(Ahi[ks], Bh, Sacc[nt], 0, 0, 0);
      Sacc[nt] = __builtin_amdgcn_mfma_f32_16x16x32_bf16(Alo[ks], Bh, Sacc[nt], 0, 0, 0);
      Sacc[nt] = __builtin_amdgcn_mfma_f32_16x16x32_bf16(Ahi[ks], Bl, Sacc[nt], 0, 0, 0);
      Sacc[nt] = __builtin_amdgcn_mfma_f32_16x16x32_bf16(Alo[ks], Bl, Sacc[nt], 0, 0, 0);
    }
  }

#pragma unroll
  for (int i = 0; i < 4; ++i) {
    float bv = -INFINITY, sbv = -INFINITY;
    int bidx = 0;
#pragma unroll
    for (int nt = 0; nt < 4; ++nt) {
      int nn = nt * 16 + l15;
      float v = Sacc[nt][i];
      if (v > bv) { sbv = bv; bv = v; bidx = nn; }
      else        { sbv = fmaxf(sbv, v); }
      float nv = -v;
      if (nv > bv) { sbv = bv; bv = nv; bidx = nn + 64; }
      else         { sbv = fmaxf(sbv, nv); }
    }
#pragma unroll
    for (int h = 1; h <= 8; h <<= 1) {
      float obv = __shfl_xor(bv, h, 64);
      float osb = __shfl_xor(sbv, h, 64);
      int   obi = __shfl_xor(bidx, h, 64);
      if (obv > bv)        { sbv = fmaxf(bv, osb); bv = obv; bidx = obi; }
      else if (obv == bv)  { sbv = bv; bidx = min(bidx, obi); }
      else                 { sbv = fmaxf(sbv, obv); }
    }
    const int trow = t0 + w * 16 + qd * 4 + i;
    const float Sx = sxs[w * 16 + qd * 4 + i];
    if (bv - sbv < 2.5e-4f * Sx) {
      const float* xr2 = x + ((size_t)b * TLEN + trow) * DIM;
      const float* pt = proj_t + (size_t)r * 4096;
      double db = -1e300; int dbi = 0;
#pragma unroll
      for (int nt = 0; nt < 4; ++nt) {
        int nn = nt * 16 + l15;
        double s = 0.0;
        for (int d = 0; d < 64; ++d)
          s = fma((double)xr2[d], (double)pt[nn * 64 + d], s);
        if (s > db || (s == db && nn < dbi)) { db = s; dbi = nn; }
        double ns = -s; int nsi = nn + 64;
        if (ns > db || (ns == db && nsi < dbi)) { db = ns; dbi = nsi; }
      }
#pragma unroll
      for (int h = 1; h <= 8; h <<= 1) {
        double od = __shfl_xor(db, h, 64);
        int    oi = __shfl_xor(dbi, h, 64);
        if (od > db || (od == db && oi < dbi)) { db = od; dbi = oi; }
      }
      bidx = dbi;
    }
    if (l15 == 0)
      buckets[((size_t)b * NHASH + r) * TLEN + trow] = bidx;
  }
}

// ---------------------------------------------------------------------------
// Stable counting sort per (b,r) (unchanged, verified).
// ---------------------------------------------------------------------------
__global__ __launch_bounds__(64)
void sort_kernel(const int* __restrict__ buckets, int* __restrict__ sticker,
                 int* __restrict__ pos) {
  __shared__ int lhist[64][129];
  __shared__ int starts[128];
  const int lane = threadIdx.x;
  const int br = blockIdx.x;
  const int* bk = buckets + (size_t)br * TLEN;
  int* st = sticker + (size_t)br * TLEN;
  int* ps = pos ? pos + (size_t)br * TLEN : nullptr;

  for (int i = 0; i < 128; ++i) lhist[lane][i] = 0;
  __syncthreads();
  for (int i = 0; i < 64; ++i) lhist[lane][bk[lane * 64 + i]]++;
  __syncthreads();

  int tot0 = 0, tot1 = 0;
  for (int c = 0; c < 64; ++c) {
    int v0 = lhist[c][lane];      lhist[c][lane]      = tot0; tot0 += v0;
    int v1 = lhist[c][lane + 64]; lhist[c][lane + 64] = tot1; tot1 += v1;
  }
  int s0 = tot0;
  for (int off = 1; off < 64; off <<= 1) {
    int u = __shfl_up(s0, off, 64);
    if (lane >= off) s0 += u;
  }
  int total0 = __shfl(s0, 63, 64);
  int s1 = tot1;
  for (int off = 1; off < 64; off <<= 1) {
    int u = __shfl_up(s1, off, 64);
    if (lane >= off) s1 += u;
  }
  starts[lane] = s0 - tot0;
  starts[lane + 64] = s1 - tot1 + total0;
  __syncthreads();

  for (int i = 0; i < 64; ++i) {
    int e = lane * 64 + i;
    int bb = bk[e];
    int c = lhist[lane][bb];
    lhist[lane][bb] = c + 1;
    int sp = starts[bb] + c;
    st[sp] = e;
    if (ps) ps[e] = sp;
  }
}

// ---------------------------------------------------------------------------
// MFMA attention (round-12): SWAPPED QK^T (S^T = K.Q^T; A/B frag layouts are
// identical for 16x16x32 so operand swap is free) + key-permuted MFMA tiles:
// tile nt, row m holds key sigma(nt,m) = 32*(nt&3) + 4*(nt>>2) + 8*(m>>2) +
// (m&3). With that permutation, lane group qd ends up holding EXACTLY the
// keys 32*ks + 8*qd + j that its PV A-fragment needs -> P never leaves
// registers: no P LDS round-trip, no cross-lane data movement, one barrier
// removed. P hi/lo packing via v_cvt_pk_bf16_f32 (RNE).
// invZ deferred to the O epilogue. r11 BUG FIX: the lane's softmax state is
// for q-row l15, but Oacc rows are qd*4+i -> redistribute invZ with four
// width-16 shuffles (Z is qd-uniform after the xor16/32 reduction) before
// applying it in the epilogue.
// Khi/Klo granule swizzle g ^ ((row ^ (row>>1)) & 7) keeps the permuted
// 16-key tile reads 2-way (free) on banks.
// ---------------------------------------------------------------------------
__global__ __launch_bounds__(256, 2)
void attn_kernel(const unsigned short* __restrict__ qh, const unsigned short* __restrict__ ql,
                 const unsigned short* __restrict__ kh, const unsigned short* __restrict__ kl,
                 const unsigned short* __restrict__ vh,
                 const int* __restrict__ sticker_q, const int* __restrict__ sticker_k,
                 unsigned short* __restrict__ so_buf, float* __restrict__ slse_buf,
                 int b_off) {
  __shared__ __align__(16) unsigned short Khi[128 * 64];  // 16 KB
  __shared__ __align__(16) unsigned short Klo[128 * 64];  // 16 KB
  __shared__ __align__(16) unsigned short VtS[64 * 128];  // 16 KB, Vt[d][key]

  const int tid = threadIdx.x;
  const int w = tid >> 6;
  const int l = tid & 63;
  const int l15 = l & 15;
  const int qd = l >> 4;
  const int n = blockIdx.x, r = blockIdx.y, bl = blockIdx.z;
  const int b = b_off + bl;
  const size_t brbase = ((size_t)b * NHASH + r) * TLEN;
  const size_t obase  = ((size_t)bl * NHASH + r) * TLEN;
  const int nprev = (n + NBUCK - 1) & (NBUCK - 1);

  // ---- stage K hi/lo: pure short8 copies; granule swizzle g ^ f(row),
  //      f(row) = (row ^ (row>>1)) & 7
  for (int it = 0; it < 4; ++it) {
    int idx = it * 256 + tid;         // 1024 = 128 rows x 8 granules
    int row = idx >> 3, gc = idx & 7;
    int srow = (row < 64) ? (nprev * 64 + row) : (n * 64 + (row - 64));
    int ik = sticker_k[brbase + srow];
    size_t src = ((size_t)bl * TLEN + ik) * DIM + gc * 8;
    int fr = (row ^ (row >> 1)) & 7;
    int o = (row << 6) + ((gc ^ fr) << 3);
    *(short8*)&Khi[o] = *(const short8*)(kh + src);
    *(short8*)&Klo[o] = *(const short8*)(kl + src);
  }
  // ---- stage V transposed, key-major lanes (unchanged)
  for (int it = 0; it < 4; ++it) {
    int idx = it * 256 + tid;         // 1024 = 128 keys x 8 d-groups
    int key = idx & 127, dg = idx >> 7;
    int srow = (key < 64) ? (nprev * 64 + key) : (n * 64 + (key - 64));
    int ik = sticker_k[brbase + srow];
    ushort8 vv = *(const ushort8*)(vh + ((size_t)bl * TLEN + ik) * DIM + dg * 8);
    int kg = key >> 3, kr = key & 7;
#pragma unroll
    for (int e = 0; e < 8; ++e) {
      int d = dg * 8 + e;
      VtS[d * 128 + ((kg ^ (d & 15)) << 3) + kr] = vv[e];
    }
  }

  // ---- Q fragments: direct short8 loads (pre-scaled, pre-split)
  const int torig = sticker_q[brbase + n * 64 + w * 16 + l15];
  short8 Ahi[2], Alo[2];
#pragma unroll
  for (int ks = 0; ks < 2; ++ks) {
    size_t src = ((size_t)bl * TLEN + torig) * DIM + ks * 32 + qd * 8;
    Ahi[ks] = *(const short8*)(qh + src);
    Alo[ks] = *(const short8*)(ql + src);
  }
  __syncthreads();

  // ---- swapped QK^T: S^T tiles, bf16x3. Tile nt row l15 <- key
  //      32*(nt&3) + 4*(nt>>2) + kp, kp = 8*(l15>>2) + (l15&3).
  //      Output: lane (qd,l15) reg i of tile nt = P[key = 32*(nt&3) +
  //      4*(nt>>2) + 8*qd + i][qrow = l15].
  const int kp = ((l15 >> 2) << 3) + (l15 & 3);
  float4v Sacc[8];
#pragma unroll
  for (int nt = 0; nt < 8; ++nt) {
    float4v z = {0.f, 0.f, 0.f, 0.f};
    Sacc[nt] = z;
    int key = ((nt & 3) << 5) + ((nt >> 2) << 2) + kp;
    int fk = (key ^ (key >> 1)) & 7;
#pragma unroll
    for (int ksd = 0; ksd < 2; ++ksd) {
      int gk = ksd * 4 + qd;
      int o = (key << 6) + ((gk ^ fk) << 3);
      short8 Bh = *(const short8*)&Khi[o];
      short8 Bl = *(const short8*)&Klo[o];
      // terms: Kh.Qh, Kh.Ql, Kl.Qh == same three products, same order as r10
      Sacc[nt] = __builtin_amdgcn_mfma_f32_16x16x32_bf16(Bh, Ahi[ksd], Sacc[nt], 0, 0, 0);
      Sacc[nt] = __builtin_amdgcn_mfma_f32_16x16x32_bf16(Bh, Alo[ksd], Sacc[nt], 0, 0, 0);
      Sacc[nt] = __builtin_amdgcn_mfma_f32_16x16x32_bf16(Bl, Ahi[ksd], Sacc[nt], 0, 0, 0);
    }
  }

  // ---- softmax for qrow = l15: 32 in-register keys per lane + 2 shuffles
  float mA = -INFINITY, mB = -INFINITY;
#pragma unroll
  for (int nt = 0; nt < 8; nt += 2) {
    mA = fmaxf(mA, fmaxf(fmaxf(Sacc[nt][0], Sacc[nt][1]),
                         fmaxf(Sacc[nt][2], Sacc[nt][3])));
    mB = fmaxf(mB, fmaxf(fmaxf(Sacc[nt + 1][0], Sacc[nt + 1][1]),
                         fmaxf(Sacc[nt + 1][2], Sacc[nt + 1][3])));
  }
  float m = fmaxf(mA, mB);
  m = fmaxf(m, __shfl_xor(m, 16, 64));
  m = fmaxf(m, __shfl_xor(m, 32, 64));

  // exp + immediate bf16 hi/lo pack (P left unnormalized; invZ in epilogue)
  unsigned hw[8][2], lw[8][2];
  float Zp0 = 0.f, Zp1 = 0.f, Zp2 = 0.f, Zp3 = 0.f;
#pragma unroll
  for (int nt = 0; nt < 8; ++nt) {
    float e0 = __expf(Sacc[nt][0] - m);
    float e1 = __expf(Sacc[nt][1] - m);
    float e2 = __expf(Sacc[nt][2] - m);
    float e3 = __expf(Sacc[nt][3] - m);
    Zp0 += e0; Zp1 += e1; Zp2 += e2; Zp3 += e3;
    unsigned h0, h1, l0, l1;
    asm("v_cvt_pk_bf16_f32 %0, %1, %2" : "=v"(h0) : "v"(e0), "v"(e1));
    float r0 = e0 - __uint_as_float(h0 << 16);
    float r1 = e1 - __uint_as_float(h0 & 0xFFFF0000u);
    asm("v_cvt_pk_bf16_f32 %0, %1, %2" : "=v"(l0) : "v"(r0), "v"(r1));
    asm("v_cvt_pk_bf16_f32 %0, %1, %2" : "=v"(h1) : "v"(e2), "v"(e3));
    float r2 = e2 - __uint_as_float(h1 << 16);
    float r3 = e3 - __uint_as_float(h1 & 0xFFFF0000u);
    asm("v_cvt_pk_bf16_f32 %0, %1, %2" : "=v"(l1) : "v"(r2), "v"(r3));
    hw[nt][0] = h0; hw[nt][1] = h1;
    lw[nt][0] = l0; lw[nt][1] = l1;
  }
  float Z = (Zp0 + Zp1) + (Zp2 + Zp3);
  Z += __shfl_xor(Z, 16, 64);
  Z += __shfl_xor(Z, 32, 64);
  const float invZ = 1.0f / Z;
  if (qd == 0)
    slse_buf[brbase + n * 64 + w * 16 + l15] = m + __logf(Z);

  // ---- r12 fix: Oacc rows are q-rows qd*4+i, but this lane's invZ is for
  //      q-row l15. Pull the right rows' invZ (qd-uniform) via width-16 shfl.
  float zr[4];
#pragma unroll
  for (int i = 0; i < 4; ++i) zr[i] = __shfl(invZ, qd * 4 + i, 16);

  // ---- assemble PV A-fragments: fully lane-local thanks to sigma.
  //      frag ks element j: j=0..3 <- tile ks reg j; j=4..7 <- tile ks+4 reg j-4
  short8 PhA[4], PlA[4];
#pragma unroll
  for (int ks = 0; ks < 4; ++ks) {
    union { uint4v u; short8 s; } uh, ul;
    uh.u = (uint4v){hw[ks][0], hw[ks][1], hw[ks + 4][0], hw[ks + 4][1]};
    ul.u = (uint4v){lw[ks][0], lw[ks][1], lw[ks + 4][0], lw[ks + 4][1]};
    PhA[ks] = uh.s;
    PlA[ks] = ul.s;
  }

  // ---- PV: O[16 x 64] per wave; A from registers, B from VtS (unchanged)
  float4v Oacc[4];
#pragma unroll
  for (int dt = 0; dt < 4; ++dt) { float4v z = {0.f, 0.f, 0.f, 0.f}; Oacc[dt] = z; }
#pragma unroll
  for (int ks = 0; ks < 4; ++ks) {
#pragma unroll
    for (int dt = 0; dt < 4; ++dt) {
      int vrow = dt * 16 + l15;
      int gv = (ks * 4 + qd) ^ (vrow & 15);
      short8 Bv = *(const short8*)&VtS[vrow * 128 + (gv << 3)];
      Oacc[dt] = __builtin_amdgcn_mfma_f32_16x16x32_bf16(PhA[ks], Bv, Oacc[dt], 0, 0, 0);
      Oacc[dt] = __builtin_amdgcn_mfma_f32_16x16x32_bf16(PlA[ks], Bv, Oacc[dt], 0, 0, 0);
    }
  }

  // ---- epilogue: sorted-order bf16 store (row-correct invZ applied here)
#pragma unroll
  for (int dt = 0; dt < 4; ++dt) {
#pragma unroll
    for (int i = 0; i < 4; ++i) {
      int orow = n * 64 + w * 16 + qd * 4 + i;
      so_buf[(obase + orow) * DIM + dt * 16 + l15] = bf16_rne(Oacc[dt][i] * zr[i]);
    }
  }
}

// ---------------------------------------------------------------------------
// Combine the 8 hash rounds (gather via pos_q); so_buf bf16.
// ---------------------------------------------------------------------------
__global__ __launch_bounds__(256)
void combine_kernel(const unsigned short* __restrict__ so_buf,
                    const float* __restrict__ slse_buf,
                    const int* __restrict__ pos_q, float* __restrict__ out, int b_off) {
  const size_t tid = (size_t)blockIdx.x * 256 + threadIdx.x;  // CB*T*8
  const size_t bt = tid >> 3;
  const int g = (int)(tid & 7);
  const size_t bl = bt >> 12;
  const size_t t = bt & 4095;
  const size_t b = b_off + bl;

  int pp[8];
  float l[8];
  float M = -INFINITY;
#pragma unroll
  for (int rr = 0; rr < 8; ++rr) {
    pp[rr] = pos_q[(b * NHASH + rr) * TLEN + t];
    l[rr] = slse_buf[(b * NHASH + rr) * TLEN + pp[rr]];
    M = fmaxf(M, l[rr]);
  }
  float Z = 0.f;
  float w[8];
#pragma unroll
  for (int rr = 0; rr < 8; ++rr) { w[rr] = __expf(l[rr] - M); Z += w[rr]; }
  const float invZ = 1.0f / Z;

  float s[8] = {0.f, 0.f, 0.f, 0.f, 0.f, 0.f, 0.f, 0.f};
#pragma unroll
  for (int rr = 0; rr < 8; ++rr) {
    ushort8 ov = *(const ushort8*)(so_buf +
        ((bl * NHASH + rr) * TLEN + (size_t)pp[rr]) * DIM + g * 8);
#pragma unroll
    for (int j = 0; j < 8; ++j)
      s[j] = fmaf(w[rr], bf16_to_f32(ov[j]), s[j]);
  }
  float* op = out + (b * TLEN + t) * DIM + g * 8;
  float4 o0 = make_float4(s[0] * invZ, s[1] * invZ, s[2] * invZ, s[3] * invZ);
  float4 o1 = make_float4(s[4] * invZ, s[5] * invZ, s[6] * invZ, s[7] * invZ);
  *(float4*)op = o0;
  *(float4*)(op + 4) = o1;
}

// ---------------------------------------------------------------------------
// Workspace layout (adaptive):
//   [0,4) sticker_q  [4,8) sticker_k  [8,12) pos_q  [12,16) slse   (MB)
//   [16MB,+192KB) pjh/pjl/proj_t (prep outputs)
//   [17,21) buckets_q  [21,25) buckets_k            (hash/sort phase)
//   chunk region from 17MB (reused after sorts):
//     so_buf bf16 CB*4MB | qh,ql,kh,kl,vh bf16 CB*0.5MB each
//   total = 17 + 6.5*CB MB;  CB in {32..1} largest fitting (min 23.5 MB).
// ---------------------------------------------------------------------------
extern "C" void kernel_launch(void* const* d_in, const int* in_sizes, int n_in,
                              void* d_out, int out_size, void* d_ws, size_t ws_size,
                              hipStream_t stream) {
  const float* q = (const float*)d_in[0];
  const float* k = (const float*)d_in[1];
  const float* v = (const float*)d_in[2];
  const float* proj = (const float*)d_in[3];
  float* out = (float*)d_out;

  char* ws = (char*)d_ws;
  const size_t MB = (size_t)1 << 20;
  const size_t KB = (size_t)1 << 10;
  int* sticker_q = (int*)(ws + 0 * MB);
  int* sticker_k = (int*)(ws + 4 * MB);
  int* pos_q     = (int*)(ws + 8 * MB);
  float* slse_buf = (float*)(ws + 12 * MB);
  unsigned short* pjh = (unsigned short*)(ws + 16 * MB);
  unsigned short* pjl = (unsigned short*)(ws + 16 * MB + 64 * KB);
  float* proj_t  = (float*)(ws + 16 * MB + 128 * KB);
  int* buckets_q = (int*)(ws + 17 * MB);
  int* buckets_k = (int*)(ws + 21 * MB);

  int CB = 32;
  while (CB > 1 && 17 * MB + (size_t)CB * 13 * MB / 2 > ws_size) CB >>= 1;

  char* chunk = ws + 17 * MB;
  unsigned short* so_buf = (unsigned short*)chunk;
  unsigned short* qh = (unsigned short*)(chunk + (size_t)CB * 4 * MB);
  unsigned short* ql = (unsigned short*)(chunk + (size_t)CB * 9 * MB / 2);
  unsigned short* kh = (unsigned short*)(chunk + (size_t)CB * 5 * MB);
  unsigned short* kl = (unsigned short*)(chunk + (size_t)CB * 11 * MB / 2);
  unsigned short* vh = (unsigned short*)(chunk + (size_t)CB * 6 * MB);

  prep_kernel<<<dim3(NHASH), 256, 0, stream>>>(proj, pjh, pjl, proj_t);
  hash_kernel<<<dim3(TLEN / 64, NHASH, BATCH), 256, 0, stream>>>(q, proj_t, pjh, pjl, buckets_q);
  hash_kernel<<<dim3(TLEN / 64, NHASH, BATCH), 256, 0, stream>>>(k, proj_t, pjh, pjl, buckets_k);
  sort_kernel<<<dim3(BATCH * NHASH), 64, 0, stream>>>(buckets_q, sticker_q, pos_q);
  sort_kernel<<<dim3(BATCH * NHASH), 64, 0, stream>>>(buckets_k, sticker_k, nullptr);

  for (int b_off = 0; b_off < BATCH; b_off += CB) {
    convert_kernel<<<dim3(CB * 128, 3), 256, 0, stream>>>(q, k, v, qh, ql, kh, kl, vh, b_off);
    attn_kernel<<<dim3(NBUCK, NHASH, CB), 256, 0, stream>>>(
        qh, ql, kh, kl, vh, sticker_q, sticker_k, so_buf, slse_buf, b_off);
    combine_kernel<<<dim3(CB * TLEN * 8 / 256), 256, 0, stream>>>(
        so_buf, slse_buf, pos_q, out, b_off);
  }
}

// Round 3
// 478.791 us; speedup vs baseline: 1.2311x; 1.2311x over previous
//
#include <hip/hip_runtime.h>
#include <math.h>

#define BATCH 32
#define TLEN  4096
#define DIM   64
#define NHASH 8
#define NBUCK 64   // n_buckets
#define BSIZE 64   // bucket size

typedef __attribute__((ext_vector_type(8))) short short8;
typedef __attribute__((ext_vector_type(8))) unsigned short ushort8;
typedef __attribute__((ext_vector_type(4))) float float4v;
typedef __attribute__((ext_vector_type(4))) unsigned int uint4v;

__device__ inline unsigned short bf16_rne(float x) {
  unsigned u = __float_as_uint(x);
  u += 0x7FFFu + ((u >> 16) & 1u);
  return (unsigned short)(u >> 16);
}
__device__ inline float bf16_to_f32(unsigned short h) {
  return __uint_as_float(((unsigned)h) << 16);
}

// ---------------------------------------------------------------------------
// Prep kernel (one-time, 8 blocks): transpose + bf16-split proj (verified r9).
// ---------------------------------------------------------------------------
__global__ __launch_bounds__(256)
void prep_kernel(const float* __restrict__ proj, unsigned short* __restrict__ pjh,
                 unsigned short* __restrict__ pjl, float* __restrict__ proj_t) {
  const int r = blockIdx.x;
  const int tid = threadIdx.x;
  for (int kk = 0; kk < 16; ++kk) {
    int idx = kk * 256 + tid;        // 4096 = 64d x 64n
    int d = idx >> 6, nn = idx & 63;
    float val = proj[d * 512 + r * 64 + nn];
    unsigned short hb = bf16_rne(val);
    unsigned short lb = bf16_rne(val - bf16_to_f32(hb));
    int g = d >> 3, e = d & 7;
    int o = (nn << 6) + ((g ^ (nn & 7)) << 3) + e;
    pjh[r * 4096 + o] = hb;
    pjl[r * 4096 + o] = lb;
    proj_t[r * 4096 + nn * 64 + d] = val;
  }
}

// ---------------------------------------------------------------------------
// Per-chunk bf16 split prepass (round-10): q -> qh/ql (pre-scaled 1/8),
// k -> kh/kl, v -> vh. Memory-bound. blockIdx.y selects the array.
// ---------------------------------------------------------------------------
__global__ __launch_bounds__(256)
void convert_kernel(const float* __restrict__ q, const float* __restrict__ k,
                    const float* __restrict__ v,
                    unsigned short* __restrict__ qh, unsigned short* __restrict__ ql,
                    unsigned short* __restrict__ kh, unsigned short* __restrict__ kl,
                    unsigned short* __restrict__ vh, int b_off) {
  const size_t idx = (size_t)blockIdx.x * 256 + threadIdx.x;  // CB*T*D/8 chunks
  const int which = blockIdx.y;
  const size_t soff = ((size_t)b_off * TLEN * DIM) + idx * 8;
  const size_t doff = idx * 8;
  if (which == 0) {
    float4 a = *(const float4*)(q + soff);
    float4 b = *(const float4*)(q + soff + 4);
    float vv[8] = {a.x, a.y, a.z, a.w, b.x, b.y, b.z, b.w};
    ushort8 h8, l8;
#pragma unroll
    for (int j = 0; j < 8; ++j) {
      float s = vv[j] * 0.125f;
      unsigned short hb = bf16_rne(s);
      h8[j] = hb;
      l8[j] = bf16_rne(s - bf16_to_f32(hb));
    }
    *(ushort8*)(qh + doff) = h8;
    *(ushort8*)(ql + doff) = l8;
  } else if (which == 1) {
    float4 a = *(const float4*)(k + soff);
    float4 b = *(const float4*)(k + soff + 4);
    float vv[8] = {a.x, a.y, a.z, a.w, b.x, b.y, b.z, b.w};
    ushort8 h8, l8;
#pragma unroll
    for (int j = 0; j < 8; ++j) {
      unsigned short hb = bf16_rne(vv[j]);
      h8[j] = hb;
      l8[j] = bf16_rne(vv[j] - bf16_to_f32(hb));
    }
    *(ushort8*)(kh + doff) = h8;
    *(ushort8*)(kl + doff) = l8;
  } else {
    float4 a = *(const float4*)(v + soff);
    float4 b = *(const float4*)(v + soff + 4);
    float vv[8] = {a.x, a.y, a.z, a.w, b.x, b.y, b.z, b.w};
    ushort8 h8;
#pragma unroll
    for (int j = 0; j < 8; ++j) h8[j] = bf16_rne(vv[j]);
    *(ushort8*)(vh + doff) = h8;
  }
}

// ---------------------------------------------------------------------------
// MFMA hash kernel (round-13): SWAPPED operands — mfma(proj, x) gives
// S^T[color][t]: each lane holds 16 colors for ONE t-row (col = l15), so the
// argmax runs once (not 4x) with an in-register |d| top-2 (sign folded into
// the candidate index; exact ties always produce margin 0 -> f64 fallback, so
// MFMA-path tie-breaks are don't-cares) + 2 shuffle rounds across qd.
// S bit-identical to r9 (same products, same accumulation order; operand-swap
// neutrality proven by r12's unchanged absmax). f64 fallback is now a
// ballot-driven per-row loop: all 64 lanes cooperate (lane l owns colors l /
// l+64), same FMA order, same min-idx tie-break -> decisions bit-equivalent.
// sxs LDS round-trip removed (sxp is already per-l15-row after xor-reduce).
// ---------------------------------------------------------------------------
__global__ __launch_bounds__(256, 2)
void hash_kernel(const float* __restrict__ x, const float* __restrict__ proj_t,
                 const unsigned short* __restrict__ pjh,
                 const unsigned short* __restrict__ pjl,
                 int* __restrict__ buckets) {
  __shared__ __align__(16) unsigned short pbh[64 * 64];
  __shared__ __align__(16) unsigned short pbl[64 * 64];

  const int tid = threadIdx.x;
  const int w = tid >> 6;
  const int l = tid & 63;
  const int l15 = l & 15;
  const int qd = l >> 4;
  const int r = blockIdx.y, b = blockIdx.z;
  const int t0 = blockIdx.x << 6;

  const unsigned short* gh = pjh + (size_t)r * 4096;
  const unsigned short* gl = pjl + (size_t)r * 4096;
#pragma unroll
  for (int it = 0; it < 2; ++it) {
    int idx = it * 256 + tid;
    *(short8*)&pbh[idx * 8] = *(const short8*)&gh[idx * 8];
    *(short8*)&pbl[idx * 8] = *(const short8*)&gl[idx * 8];
  }

  // x fragments for row (t0 + w*16 + l15), d-slice qd*8..+7 per ks
  const int trow_a = t0 + w * 16 + l15;
  const float* xra = x + ((size_t)b * TLEN + trow_a) * DIM;
  short8 Ahi[2], Alo[2];
  float sxp = 0.f;
#pragma unroll
  for (int ks = 0; ks < 2; ++ks) {
    float4 x0 = *(const float4*)(xra + ks * 32 + qd * 8);
    float4 x1 = *(const float4*)(xra + ks * 32 + qd * 8 + 4);
    sxp += fabsf(x0.x) + fabsf(x0.y) + fabsf(x0.z) + fabsf(x0.w)
         + fabsf(x1.x) + fabsf(x1.y) + fabsf(x1.z) + fabsf(x1.w);
    float v[8] = {x0.x, x0.y, x0.z, x0.w, x1.x, x1.y, x1.z, x1.w};
#pragma unroll
    for (int j = 0; j < 8; ++j) {
      unsigned short hb = bf16_rne(v[j]);
      Ahi[ks][j] = (short)hb;
      Alo[ks][j] = (short)bf16_rne(v[j] - bf16_to_f32(hb));
    }
  }
  // full Sigma|x| of row l15, uniform across qd
  sxp += __shfl_xor(sxp, 16, 64);
  sxp += __shfl_xor(sxp, 32, 64);
  __syncthreads();   // pbh/pbl staged

  // swapped MFMA: tile nt covers colors nt*16..+15 (rows), t-cols = l15.
  // A-frag = proj rows nn = nt*16+l15 (same fragment bytes as the old B-frag);
  // B-frag = x (same bytes as the old A-frag). Term order preserved.
  float4v Sacc[4];
#pragma unroll
  for (int nt = 0; nt < 4; ++nt) {
    float4v z = {0.f, 0.f, 0.f, 0.f};
    Sacc[nt] = z;
#pragma unroll
    for (int ks = 0; ks < 2; ++ks) {
      int nn = nt * 16 + l15;
      int gk = ks * 4 + qd;
      int o = (nn << 6) + ((gk ^ (nn & 7)) << 3);
      short8 Bh = *(const short8*)&pbh[o];
      short8 Bl = *(const short8*)&pbl[o];
      Sacc[nt] = __builtin_amdgcn_mfma_f32_16x16x32_bf16(Bh, Ahi[ks], Sacc[nt], 0, 0, 0);
      Sacc[nt] = __builtin_amdgcn_mfma_f32_16x16x32_bf16(Bh, Alo[ks], Sacc[nt], 0, 0, 0);
      Sacc[nt] = __builtin_amdgcn_mfma_f32_16x16x32_bf16(Bl, Ahi[ks], Sacc[nt], 0, 0, 0);
      Sacc[nt] = __builtin_amdgcn_mfma_f32_16x16x32_bf16(Bl, Alo[ks], Sacc[nt], 0, 0, 0);
    }
  }

  // in-register top-2 over this lane's 16 colors (|d|; sign -> index bit 6)
  float bv = -INFINITY, sbv = -INFINITY;
  int bidx = 0;
#pragma unroll
  for (int nt = 0; nt < 4; ++nt) {
#pragma unroll
    for (int i = 0; i < 4; ++i) {
      float d = Sacc[nt][i];
      float a = fabsf(d);
      int idx2 = nt * 16 + qd * 4 + i + (int)((__float_as_uint(d) >> 25) & 64u);
      float nsb = fmaxf(fminf(a, bv), sbv);   // new 2nd-best given OLD bv
      bidx = (a > bv) ? idx2 : bidx;
      bv = fmaxf(a, bv);
      sbv = nsb;
    }
  }
  // reduce across the 4 qd groups (colors are partitioned by qd within tiles)
#pragma unroll
  for (int h = 16; h <= 32; h <<= 1) {
    float obv = __shfl_xor(bv, h, 64);
    float osb = __shfl_xor(sbv, h, 64);
    int   obi = __shfl_xor(bidx, h, 64);
    float nsb = fmaxf(fmaxf(sbv, osb), fminf(bv, obv));
    bidx = (obv > bv) ? obi : bidx;
    bv = fmaxf(bv, obv);
    sbv = nsb;
  }

  // exact f64 fallback for rows inside the rigorous margin (wave-uniform loop)
  bool needf = (bv - sbv) < 2.5e-4f * sxp;
  unsigned long long need = __ballot(needf);
  unsigned rows = (unsigned)(need & 0xFFFFull);   // qd==0 copies
  if (rows) {
    const float* pt = proj_t + (size_t)r * 4096;
    while (rows) {
      int rr = __ffs(rows) - 1;
      rows &= rows - 1;
      const float* xr2 = x + ((size_t)b * TLEN + (t0 + w * 16 + rr)) * DIM;
      double s = 0.0;
      for (int d = 0; d < 64; ++d)
        s = fma((double)xr2[d], (double)pt[l * 64 + d], s);
      double b1 = fabs(s);
      int i1 = (s >= -s) ? l : l + 64;
#pragma unroll
      for (int h = 1; h <= 32; h <<= 1) {
        double ob = __shfl_xor(b1, h, 64);
        int    oi = __shfl_xor(i1, h, 64);
        if (ob > b1 || (ob == b1 && oi < i1)) { b1 = ob; i1 = oi; }
      }
      if (l15 == rr) bidx = i1;
    }
  }

  if (qd == 0)
    buckets[((size_t)b * NHASH + r) * TLEN + t0 + w * 16 + l15] = bidx;
}

// ---------------------------------------------------------------------------
// Stable counting sort per (b,r) (unchanged, verified).
// ---------------------------------------------------------------------------
__global__ __launch_bounds__(64)
void sort_kernel(const int* __restrict__ buckets, int* __restrict__ sticker,
                 int* __restrict__ pos) {
  __shared__ int lhist[64][129];
  __shared__ int starts[128];
  const int lane = threadIdx.x;
  const int br = blockIdx.x;
  const int* bk = buckets + (size_t)br * TLEN;
  int* st = sticker + (size_t)br * TLEN;
  int* ps = pos ? pos + (size_t)br * TLEN : nullptr;

  for (int i = 0; i < 128; ++i) lhist[lane][i] = 0;
  __syncthreads();
  for (int i = 0; i < 64; ++i) lhist[lane][bk[lane * 64 + i]]++;
  __syncthreads();

  int tot0 = 0, tot1 = 0;
  for (int c = 0; c < 64; ++c) {
    int v0 = lhist[c][lane];      lhist[c][lane]      = tot0; tot0 += v0;
    int v1 = lhist[c][lane + 64]; lhist[c][lane + 64] = tot1; tot1 += v1;
  }
  int s0 = tot0;
  for (int off = 1; off < 64; off <<= 1) {
    int u = __shfl_up(s0, off, 64);
    if (lane >= off) s0 += u;
  }
  int total0 = __shfl(s0, 63, 64);
  int s1 = tot1;
  for (int off = 1; off < 64; off <<= 1) {
    int u = __shfl_up(s1, off, 64);
    if (lane >= off) s1 += u;
  }
  starts[lane] = s0 - tot0;
  starts[lane + 64] = s1 - tot1 + total0;
  __syncthreads();

  for (int i = 0; i < 64; ++i) {
    int e = lane * 64 + i;
    int bb = bk[e];
    int c = lhist[lane][bb];
    lhist[lane][bb] = c + 1;
    int sp = starts[bb] + c;
    st[sp] = e;
    if (ps) ps[e] = sp;
  }
}

// ---------------------------------------------------------------------------
// MFMA attention (round-13): r12 structure (swapped QK^T, key-permuted sigma
// tiles, in-register P, deferred row-correct invZ) with P-lo DROPPED in PV:
// P is plain bf16 (RNE via v_cvt_pk_bf16_f32). Removes the residual pack
// (~10 ops/nt) and halves PV MFMAs (32 -> 16). Error bound: |Sum Pl*V|/Z
// <= 2^-9 * <|V|>_P ~ 0.002 typical, <= 0.009 worst-case -> within the
// 0.0231 threshold on top of the existing 0.0078 bf16-output floor.
// ---------------------------------------------------------------------------
__global__ __launch_bounds__(256, 2)
void attn_kernel(const unsigned short* __restrict__ qh, const unsigned short* __restrict__ ql,
                 const unsigned short* __restrict__ kh, const unsigned short* __restrict__ kl,
                 const unsigned short* __restrict__ vh,
                 const int* __restrict__ sticker_q, const int* __restrict__ sticker_k,
                 unsigned short* __restrict__ so_buf, float* __restrict__ slse_buf,
                 int b_off) {
  __shared__ __align__(16) unsigned short Khi[128 * 64];  // 16 KB
  __shared__ __align__(16) unsigned short Klo[128 * 64];  // 16 KB
  __shared__ __align__(16) unsigned short VtS[64 * 128];  // 16 KB, Vt[d][key]

  const int tid = threadIdx.x;
  const int w = tid >> 6;
  const int l = tid & 63;
  const int l15 = l & 15;
  const int qd = l >> 4;
  const int n = blockIdx.x, r = blockIdx.y, bl = blockIdx.z;
  const int b = b_off + bl;
  const size_t brbase = ((size_t)b * NHASH + r) * TLEN;
  const size_t obase  = ((size_t)bl * NHASH + r) * TLEN;
  const int nprev = (n + NBUCK - 1) & (NBUCK - 1);

  // ---- stage K hi/lo: pure short8 copies; granule swizzle g ^ f(row),
  //      f(row) = (row ^ (row>>1)) & 7
  for (int it = 0; it < 4; ++it) {
    int idx = it * 256 + tid;         // 1024 = 128 rows x 8 granules
    int row = idx >> 3, gc = idx & 7;
    int srow = (row < 64) ? (nprev * 64 + row) : (n * 64 + (row - 64));
    int ik = sticker_k[brbase + srow];
    size_t src = ((size_t)bl * TLEN + ik) * DIM + gc * 8;
    int fr = (row ^ (row >> 1)) & 7;
    int o = (row << 6) + ((gc ^ fr) << 3);
    *(short8*)&Khi[o] = *(const short8*)(kh + src);
    *(short8*)&Klo[o] = *(const short8*)(kl + src);
  }
  // ---- stage V transposed, key-major lanes (unchanged)
  for (int it = 0; it < 4; ++it) {
    int idx = it * 256 + tid;         // 1024 = 128 keys x 8 d-groups
    int key = idx & 127, dg = idx >> 7;
    int srow = (key < 64) ? (nprev * 64 + key) : (n * 64 + (key - 64));
    int ik = sticker_k[brbase + srow];
    ushort8 vv = *(const ushort8*)(vh + ((size_t)bl * TLEN + ik) * DIM + dg * 8);
    int kg = key >> 3, kr = key & 7;
#pragma unroll
    for (int e = 0; e < 8; ++e) {
      int d = dg * 8 + e;
      VtS[d * 128 + ((kg ^ (d & 15)) << 3) + kr] = vv[e];
    }
  }

  // ---- Q fragments: direct short8 loads (pre-scaled, pre-split)
  const int torig = sticker_q[brbase + n * 64 + w * 16 + l15];
  short8 Ahi[2], Alo[2];
#pragma unroll
  for (int ks = 0; ks < 2; ++ks) {
    size_t src = ((size_t)bl * TLEN + torig) * DIM + ks * 32 + qd * 8;
    Ahi[ks] = *(const short8*)(qh + src);
    Alo[ks] = *(const short8*)(ql + src);
  }
  __syncthreads();

  // ---- swapped QK^T: S^T tiles, bf16x3. Tile nt row l15 <- key
  //      32*(nt&3) + 4*(nt>>2) + kp, kp = 8*(l15>>2) + (l15&3).
  //      Output: lane (qd,l15) reg i of tile nt = P[key = 32*(nt&3) +
  //      4*(nt>>2) + 8*qd + i][qrow = l15].
  const int kp = ((l15 >> 2) << 3) + (l15 & 3);
  float4v Sacc[8];
#pragma unroll
  for (int nt = 0; nt < 8; ++nt) {
    float4v z = {0.f, 0.f, 0.f, 0.f};
    Sacc[nt] = z;
    int key = ((nt & 3) << 5) + ((nt >> 2) << 2) + kp;
    int fk = (key ^ (key >> 1)) & 7;
#pragma unroll
    for (int ksd = 0; ksd < 2; ++ksd) {
      int gk = ksd * 4 + qd;
      int o = (key << 6) + ((gk ^ fk) << 3);
      short8 Bh = *(const short8*)&Khi[o];
      short8 Bl = *(const short8*)&Klo[o];
      // terms: Kh.Qh, Kh.Ql, Kl.Qh == same three products, same order as r10
      Sacc[nt] = __builtin_amdgcn_mfma_f32_16x16x32_bf16(Bh, Ahi[ksd], Sacc[nt], 0, 0, 0);
      Sacc[nt] = __builtin_amdgcn_mfma_f32_16x16x32_bf16(Bh, Alo[ksd], Sacc[nt], 0, 0, 0);
      Sacc[nt] = __builtin_amdgcn_mfma_f32_16x16x32_bf16(Bl, Ahi[ksd], Sacc[nt], 0, 0, 0);
    }
  }

  // ---- softmax for qrow = l15: 32 in-register keys per lane + 2 shuffles
  float mA = -INFINITY, mB = -INFINITY;
#pragma unroll
  for (int nt = 0; nt < 8; nt += 2) {
    mA = fmaxf(mA, fmaxf(fmaxf(Sacc[nt][0], Sacc[nt][1]),
                         fmaxf(Sacc[nt][2], Sacc[nt][3])));
    mB = fmaxf(mB, fmaxf(fmaxf(Sacc[nt + 1][0], Sacc[nt + 1][1]),
                         fmaxf(Sacc[nt + 1][2], Sacc[nt + 1][3])));
  }
  float m = fmaxf(mA, mB);
  m = fmaxf(m, __shfl_xor(m, 16, 64));
  m = fmaxf(m, __shfl_xor(m, 32, 64));

  // exp + immediate bf16 pack (P unnormalized; invZ in epilogue). Hi only.
  unsigned hw[8][2];
  float Zp0 = 0.f, Zp1 = 0.f, Zp2 = 0.f, Zp3 = 0.f;
#pragma unroll
  for (int nt = 0; nt < 8; ++nt) {
    float e0 = __expf(Sacc[nt][0] - m);
    float e1 = __expf(Sacc[nt][1] - m);
    float e2 = __expf(Sacc[nt][2] - m);
    float e3 = __expf(Sacc[nt][3] - m);
    Zp0 += e0; Zp1 += e1; Zp2 += e2; Zp3 += e3;
    unsigned h0, h1;
    asm("v_cvt_pk_bf16_f32 %0, %1, %2" : "=v"(h0) : "v"(e0), "v"(e1));
    asm("v_cvt_pk_bf16_f32 %0, %1, %2" : "=v"(h1) : "v"(e2), "v"(e3));
    hw[nt][0] = h0; hw[nt][1] = h1;
  }
  float Z = (Zp0 + Zp1) + (Zp2 + Zp3);
  Z += __shfl_xor(Z, 16, 64);
  Z += __shfl_xor(Z, 32, 64);
  const float invZ = 1.0f / Z;
  if (qd == 0)
    slse_buf[brbase + n * 64 + w * 16 + l15] = m + __logf(Z);

  // ---- Oacc rows are q-rows qd*4+i; this lane's invZ is for q-row l15.
  //      Pull the right rows' invZ (qd-uniform) via width-16 shfl.
  float zr[4];
#pragma unroll
  for (int i = 0; i < 4; ++i) zr[i] = __shfl(invZ, qd * 4 + i, 16);

  // ---- assemble PV A-fragments: fully lane-local thanks to sigma.
  //      frag ks element j: j=0..3 <- tile ks reg j; j=4..7 <- tile ks+4 reg j-4
  short8 PhA[4];
#pragma unroll
  for (int ks = 0; ks < 4; ++ks) {
    union { uint4v u; short8 s; } uh;
    uh.u = (uint4v){hw[ks][0], hw[ks][1], hw[ks + 4][0], hw[ks + 4][1]};
    PhA[ks] = uh.s;
  }

  // ---- PV: O[16 x 64] per wave; A from registers, B from VtS
  float4v Oacc[4];
#pragma unroll
  for (int dt = 0; dt < 4; ++dt) { float4v z = {0.f, 0.f, 0.f, 0.f}; Oacc[dt] = z; }
#pragma unroll
  for (int ks = 0; ks < 4; ++ks) {
#pragma unroll
    for (int dt = 0; dt < 4; ++dt) {
      int vrow = dt * 16 + l15;
      int gv = (ks * 4 + qd) ^ (vrow & 15);
      short8 Bv = *(const short8*)&VtS[vrow * 128 + (gv << 3)];
      Oacc[dt] = __builtin_amdgcn_mfma_f32_16x16x32_bf16(PhA[ks], Bv, Oacc[dt], 0, 0, 0);
    }
  }

  // ---- epilogue: sorted-order bf16 store (row-correct invZ applied here)
#pragma unroll
  for (int dt = 0; dt < 4; ++dt) {
#pragma unroll
    for (int i = 0; i < 4; ++i) {
      int orow = n * 64 + w * 16 + qd * 4 + i;
      so_buf[(obase + orow) * DIM + dt * 16 + l15] = bf16_rne(Oacc[dt][i] * zr[i]);
    }
  }
}

// ---------------------------------------------------------------------------
// Combine the 8 hash rounds (gather via pos_q); so_buf bf16.
// ---------------------------------------------------------------------------
__global__ __launch_bounds__(256)
void combine_kernel(const unsigned short* __restrict__ so_buf,
                    const float* __restrict__ slse_buf,
                    const int* __restrict__ pos_q, float* __restrict__ out, int b_off) {
  const size_t tid = (size_t)blockIdx.x * 256 + threadIdx.x;  // CB*T*8
  const size_t bt = tid >> 3;
  const int g = (int)(tid & 7);
  const size_t bl = bt >> 12;
  const size_t t = bt & 4095;
  const size_t b = b_off + bl;

  int pp[8];
  float l[8];
  float M = -INFINITY;
#pragma unroll
  for (int rr = 0; rr < 8; ++rr) {
    pp[rr] = pos_q[(b * NHASH + rr) * TLEN + t];
    l[rr] = slse_buf[(b * NHASH + rr) * TLEN + pp[rr]];
    M = fmaxf(M, l[rr]);
  }
  float Z = 0.f;
  float w[8];
#pragma unroll
  for (int rr = 0; rr < 8; ++rr) { w[rr] = __expf(l[rr] - M); Z += w[rr]; }
  const float invZ = 1.0f / Z;

  float s[8] = {0.f, 0.f, 0.f, 0.f, 0.f, 0.f, 0.f, 0.f};
#pragma unroll
  for (int rr = 0; rr < 8; ++rr) {
    ushort8 ov = *(const ushort8*)(so_buf +
        ((bl * NHASH + rr) * TLEN + (size_t)pp[rr]) * DIM + g * 8);
#pragma unroll
    for (int j = 0; j < 8; ++j)
      s[j] = fmaf(w[rr], bf16_to_f32(ov[j]), s[j]);
  }
  float* op = out + (b * TLEN + t) * DIM + g * 8;
  float4 o0 = make_float4(s[0] * invZ, s[1] * invZ, s[2] * invZ, s[3] * invZ);
  float4 o1 = make_float4(s[4] * invZ, s[5] * invZ, s[6] * invZ, s[7] * invZ);
  *(float4*)op = o0;
  *(float4*)(op + 4) = o1;
}

// ---------------------------------------------------------------------------
// Workspace layout (adaptive):
//   [0,4) sticker_q  [4,8) sticker_k  [8,12) pos_q  [12,16) slse   (MB)
//   [16MB,+192KB) pjh/pjl/proj_t (prep outputs)
//   [17,21) buckets_q  [21,25) buckets_k            (hash/sort phase)
//   chunk region from 17MB (reused after sorts):
//     so_buf bf16 CB*4MB | qh,ql,kh,kl,vh bf16 CB*0.5MB each
//   total = 17 + 6.5*CB MB;  CB in {32..1} largest fitting (min 23.5 MB).
// ---------------------------------------------------------------------------
extern "C" void kernel_launch(void* const* d_in, const int* in_sizes, int n_in,
                              void* d_out, int out_size, void* d_ws, size_t ws_size,
                              hipStream_t stream) {
  const float* q = (const float*)d_in[0];
  const float* k = (const float*)d_in[1];
  const float* v = (const float*)d_in[2];
  const float* proj = (const float*)d_in[3];
  float* out = (float*)d_out;

  char* ws = (char*)d_ws;
  const size_t MB = (size_t)1 << 20;
  const size_t KB = (size_t)1 << 10;
  int* sticker_q = (int*)(ws + 0 * MB);
  int* sticker_k = (int*)(ws + 4 * MB);
  int* pos_q     = (int*)(ws + 8 * MB);
  float* slse_buf = (float*)(ws + 12 * MB);
  unsigned short* pjh = (unsigned short*)(ws + 16 * MB);
  unsigned short* pjl = (unsigned short*)(ws + 16 * MB + 64 * KB);
  float* proj_t  = (float*)(ws + 16 * MB + 128 * KB);
  int* buckets_q = (int*)(ws + 17 * MB);
  int* buckets_k = (int*)(ws + 21 * MB);

  int CB = 32;
  while (CB > 1 && 17 * MB + (size_t)CB * 13 * MB / 2 > ws_size) CB >>= 1;

  char* chunk = ws + 17 * MB;
  unsigned short* so_buf = (unsigned short*)chunk;
  unsigned short* qh = (unsigned short*)(chunk + (size_t)CB * 4 * MB);
  unsigned short* ql = (unsigned short*)(chunk + (size_t)CB * 9 * MB / 2);
  unsigned short* kh = (unsigned short*)(chunk + (size_t)CB * 5 * MB);
  unsigned short* kl = (unsigned short*)(chunk + (size_t)CB * 11 * MB / 2);
  unsigned short* vh = (unsigned short*)(chunk + (size_t)CB * 6 * MB);

  prep_kernel<<<dim3(NHASH), 256, 0, stream>>>(proj, pjh, pjl, proj_t);
  hash_kernel<<<dim3(TLEN / 64, NHASH, BATCH), 256, 0, stream>>>(q, proj_t, pjh, pjl, buckets_q);
  hash_kernel<<<dim3(TLEN / 64, NHASH, BATCH), 256, 0, stream>>>(k, proj_t, pjh, pjl, buckets_k);
  sort_kernel<<<dim3(BATCH * NHASH), 64, 0, stream>>>(buckets_q, sticker_q, pos_q);
  sort_kernel<<<dim3(BATCH * NHASH), 64, 0, stream>>>(buckets_k, sticker_k, nullptr);

  for (int b_off = 0; b_off < BATCH; b_off += CB) {
    convert_kernel<<<dim3(CB * 128, 3), 256, 0, stream>>>(q, k, v, qh, ql, kh, kl, vh, b_off);
    attn_kernel<<<dim3(NBUCK, NHASH, CB), 256, 0, stream>>>(
        qh, ql, kh, kl, vh, sticker_q, sticker_k, so_buf, slse_buf, b_off);
    combine_kernel<<<dim3(CB * TLEN * 8 / 256), 256, 0, stream>>>(
        so_buf, slse_buf, pos_q, out, b_off);
  }
}

// Round 4
// 462.180 us; speedup vs baseline: 1.2754x; 1.0359x over previous
//
#include <hip/hip_runtime.h>
#include <math.h>

#define BATCH 32
#define TLEN  4096
#define DIM   64
#define NHASH 8
#define NBUCK 64   // n_buckets
#define BSIZE 64   // bucket size

typedef __attribute__((ext_vector_type(8))) short short8;
typedef __attribute__((ext_vector_type(8))) unsigned short ushort8;
typedef __attribute__((ext_vector_type(4))) float float4v;
typedef __attribute__((ext_vector_type(4))) unsigned int uint4v;

__device__ inline unsigned short bf16_rne(float x) {
  unsigned u = __float_as_uint(x);
  u += 0x7FFFu + ((u >> 16) & 1u);
  return (unsigned short)(u >> 16);
}
__device__ inline float bf16_to_f32(unsigned short h) {
  return __uint_as_float(((unsigned)h) << 16);
}

// ---------------------------------------------------------------------------
// Prep kernel (one-time, 8 blocks): transpose + bf16-split proj (verified r9).
// ---------------------------------------------------------------------------
__global__ __launch_bounds__(256)
void prep_kernel(const float* __restrict__ proj, unsigned short* __restrict__ pjh,
                 unsigned short* __restrict__ pjl, float* __restrict__ proj_t) {
  const int r = blockIdx.x;
  const int tid = threadIdx.x;
  for (int kk = 0; kk < 16; ++kk) {
    int idx = kk * 256 + tid;        // 4096 = 64d x 64n
    int d = idx >> 6, nn = idx & 63;
    float val = proj[d * 512 + r * 64 + nn];
    unsigned short hb = bf16_rne(val);
    unsigned short lb = bf16_rne(val - bf16_to_f32(hb));
    int g = d >> 3, e = d & 7;
    int o = (nn << 6) + ((g ^ (nn & 7)) << 3) + e;
    pjh[r * 4096 + o] = hb;
    pjl[r * 4096 + o] = lb;
    proj_t[r * 4096 + nn * 64 + d] = val;
  }
}

// ---------------------------------------------------------------------------
// Per-chunk bf16 split prepass (round-10): q -> qh/ql (pre-scaled 1/8),
// k -> kh/kl, v -> vh. Memory-bound. blockIdx.y selects the array.
// ---------------------------------------------------------------------------
__global__ __launch_bounds__(256)
void convert_kernel(const float* __restrict__ q, const float* __restrict__ k,
                    const float* __restrict__ v,
                    unsigned short* __restrict__ qh, unsigned short* __restrict__ ql,
                    unsigned short* __restrict__ kh, unsigned short* __restrict__ kl,
                    unsigned short* __restrict__ vh, int b_off) {
  const size_t idx = (size_t)blockIdx.x * 256 + threadIdx.x;  // CB*T*D/8 chunks
  const int which = blockIdx.y;
  const size_t soff = ((size_t)b_off * TLEN * DIM) + idx * 8;
  const size_t doff = idx * 8;
  if (which == 0) {
    float4 a = *(const float4*)(q + soff);
    float4 b = *(const float4*)(q + soff + 4);
    float vv[8] = {a.x, a.y, a.z, a.w, b.x, b.y, b.z, b.w};
    ushort8 h8, l8;
#pragma unroll
    for (int j = 0; j < 8; ++j) {
      float s = vv[j] * 0.125f;
      unsigned short hb = bf16_rne(s);
      h8[j] = hb;
      l8[j] = bf16_rne(s - bf16_to_f32(hb));
    }
    *(ushort8*)(qh + doff) = h8;
    *(ushort8*)(ql + doff) = l8;
  } else if (which == 1) {
    float4 a = *(const float4*)(k + soff);
    float4 b = *(const float4*)(k + soff + 4);
    float vv[8] = {a.x, a.y, a.z, a.w, b.x, b.y, b.z, b.w};
    ushort8 h8, l8;
#pragma unroll
    for (int j = 0; j < 8; ++j) {
      unsigned short hb = bf16_rne(vv[j]);
      h8[j] = hb;
      l8[j] = bf16_rne(vv[j] - bf16_to_f32(hb));
    }
    *(ushort8*)(kh + doff) = h8;
    *(ushort8*)(kl + doff) = l8;
  } else {
    float4 a = *(const float4*)(v + soff);
    float4 b = *(const float4*)(v + soff + 4);
    float vv[8] = {a.x, a.y, a.z, a.w, b.x, b.y, b.z, b.w};
    ushort8 h8;
#pragma unroll
    for (int j = 0; j < 8; ++j) h8[j] = bf16_rne(vv[j]);
    *(ushort8*)(vh + doff) = h8;
  }
}

// ---------------------------------------------------------------------------
// MFMA hash kernel (round-14): ONE block = 64 t-rows x ALL 8 hash rounds,
// q and k merged via blockIdx.z. x is loaded + bf16-split + Sigma|x|-reduced
// ONCE (was 8x redundant across the old r-grid => 256MB of x demand-reads
// per launch vs 32MB unique, plus 8x redundant split VALU). Per-r proj tiles
// are double-buffered in LDS: stage r+1 while computing r; the single
// barrier per iteration also retires round r-1's readers, so the 2-buffer
// rotation is race-free. Per-r math (MFMA terms/order, |d| top-2 argmax,
// f64 ballot fallback, tie-breaks) is byte-identical to verified r13 =>
// bucket decisions bit-equivalent.
// ---------------------------------------------------------------------------
__global__ __launch_bounds__(256, 2)
void hash_kernel(const float* __restrict__ xq, const float* __restrict__ xk,
                 const float* __restrict__ proj_t,
                 const unsigned short* __restrict__ pjh,
                 const unsigned short* __restrict__ pjl,
                 int* __restrict__ buckets_q, int* __restrict__ buckets_k) {
  __shared__ __align__(16) unsigned short pbh[2][4096];  // 8 KB x2
  __shared__ __align__(16) unsigned short pbl[2][4096];  // 8 KB x2

  const int tid = threadIdx.x;
  const int w = tid >> 6;
  const int l = tid & 63;
  const int l15 = l & 15;
  const int qd = l >> 4;
  const int b = blockIdx.y;
  const float* x = blockIdx.z ? xk : xq;
  int* buckets = blockIdx.z ? buckets_k : buckets_q;
  const int t0 = blockIdx.x << 6;

  // ---- x fragments for row (t0 + w*16 + l15), d-slice qd*8..+7 per ks (once)
  const int trow_a = t0 + w * 16 + l15;
  const float* xra = x + ((size_t)b * TLEN + trow_a) * DIM;
  short8 Ahi[2], Alo[2];
  float sxp = 0.f;
#pragma unroll
  for (int ks = 0; ks < 2; ++ks) {
    float4 x0 = *(const float4*)(xra + ks * 32 + qd * 8);
    float4 x1 = *(const float4*)(xra + ks * 32 + qd * 8 + 4);
    sxp += fabsf(x0.x) + fabsf(x0.y) + fabsf(x0.z) + fabsf(x0.w)
         + fabsf(x1.x) + fabsf(x1.y) + fabsf(x1.z) + fabsf(x1.w);
    float v[8] = {x0.x, x0.y, x0.z, x0.w, x1.x, x1.y, x1.z, x1.w};
#pragma unroll
    for (int j = 0; j < 8; ++j) {
      unsigned short hb = bf16_rne(v[j]);
      Ahi[ks][j] = (short)hb;
      Alo[ks][j] = (short)bf16_rne(v[j] - bf16_to_f32(hb));
    }
  }
  sxp += __shfl_xor(sxp, 16, 64);
  sxp += __shfl_xor(sxp, 32, 64);

  // ---- stage r=0 into buffer 0
#pragma unroll
  for (int it = 0; it < 2; ++it) {
    int idx = it * 256 + tid;
    *(short8*)&pbh[0][idx * 8] = *(const short8*)&pjh[idx * 8];
    *(short8*)&pbl[0][idx * 8] = *(const short8*)&pjl[idx * 8];
  }
  __syncthreads();

  for (int r = 0; r < NHASH; ++r) {
    const int cur = r & 1;
    // prefetch next round's proj tiles into the other buffer
    if (r < NHASH - 1) {
      const unsigned short* gh = pjh + (size_t)(r + 1) * 4096;
      const unsigned short* gl = pjl + (size_t)(r + 1) * 4096;
#pragma unroll
      for (int it = 0; it < 2; ++it) {
        int idx = it * 256 + tid;
        *(short8*)&pbh[cur ^ 1][idx * 8] = *(const short8*)&gh[idx * 8];
        *(short8*)&pbl[cur ^ 1][idx * 8] = *(const short8*)&gl[idx * 8];
      }
    }

    // swapped MFMA: tile nt covers colors nt*16..+15 (rows), t-cols = l15
    float4v Sacc[4];
#pragma unroll
    for (int nt = 0; nt < 4; ++nt) {
      float4v z = {0.f, 0.f, 0.f, 0.f};
      Sacc[nt] = z;
#pragma unroll
      for (int ks = 0; ks < 2; ++ks) {
        int nn = nt * 16 + l15;
        int gk = ks * 4 + qd;
        int o = (nn << 6) + ((gk ^ (nn & 7)) << 3);
        short8 Bh = *(const short8*)&pbh[cur][o];
        short8 Bl = *(const short8*)&pbl[cur][o];
        Sacc[nt] = __builtin_amdgcn_mfma_f32_16x16x32_bf16(Bh, Ahi[ks], Sacc[nt], 0, 0, 0);
        Sacc[nt] = __builtin_amdgcn_mfma_f32_16x16x32_bf16(Bh, Alo[ks], Sacc[nt], 0, 0, 0);
        Sacc[nt] = __builtin_amdgcn_mfma_f32_16x16x32_bf16(Bl, Ahi[ks], Sacc[nt], 0, 0, 0);
        Sacc[nt] = __builtin_amdgcn_mfma_f32_16x16x32_bf16(Bl, Alo[ks], Sacc[nt], 0, 0, 0);
      }
    }

    // in-register top-2 over this lane's 16 colors (|d|; sign -> index bit 6)
    float bv = -INFINITY, sbv = -INFINITY;
    int bidx = 0;
#pragma unroll
    for (int nt = 0; nt < 4; ++nt) {
#pragma unroll
      for (int i = 0; i < 4; ++i) {
        float d = Sacc[nt][i];
        float a = fabsf(d);
        int idx2 = nt * 16 + qd * 4 + i + (int)((__float_as_uint(d) >> 25) & 64u);
        float nsb = fmaxf(fminf(a, bv), sbv);   // new 2nd-best given OLD bv
        bidx = (a > bv) ? idx2 : bidx;
        bv = fmaxf(a, bv);
        sbv = nsb;
      }
    }
    // reduce across the 4 qd groups
#pragma unroll
    for (int h = 16; h <= 32; h <<= 1) {
      float obv = __shfl_xor(bv, h, 64);
      float osb = __shfl_xor(sbv, h, 64);
      int   obi = __shfl_xor(bidx, h, 64);
      float nsb = fmaxf(fmaxf(sbv, osb), fminf(bv, obv));
      bidx = (obv > bv) ? obi : bidx;
      bv = fmaxf(bv, obv);
      sbv = nsb;
    }

    // exact f64 fallback for rows inside the rigorous margin
    bool needf = (bv - sbv) < 2.5e-4f * sxp;
    unsigned long long need = __ballot(needf);
    unsigned rows = (unsigned)(need & 0xFFFFull);
    if (rows) {
      const float* pt = proj_t + (size_t)r * 4096;
      while (rows) {
        int rr = __ffs(rows) - 1;
        rows &= rows - 1;
        const float* xr2 = x + ((size_t)b * TLEN + (t0 + w * 16 + rr)) * DIM;
        double s = 0.0;
        for (int d = 0; d < 64; ++d)
          s = fma((double)xr2[d], (double)pt[l * 64 + d], s);
        double b1 = fabs(s);
        int i1 = (s >= -s) ? l : l + 64;
#pragma unroll
        for (int h = 1; h <= 32; h <<= 1) {
          double ob = __shfl_xor(b1, h, 64);
          int    oi = __shfl_xor(i1, h, 64);
          if (ob > b1 || (ob == b1 && oi < i1)) { b1 = ob; i1 = oi; }
        }
        if (l15 == rr) bidx = i1;
      }
    }

    if (qd == 0)
      buckets[((size_t)b * NHASH + r) * TLEN + t0 + w * 16 + l15] = bidx;

    __syncthreads();   // stage(r+1) done AND compute(r) retired on all waves
  }
}

// ---------------------------------------------------------------------------
// Stable counting sort per (b,r) (unchanged, verified).
// ---------------------------------------------------------------------------
__global__ __launch_bounds__(64)
void sort_kernel(const int* __restrict__ buckets, int* __restrict__ sticker,
                 int* __restrict__ pos) {
  __shared__ int lhist[64][129];
  __shared__ int starts[128];
  const int lane = threadIdx.x;
  const int br = blockIdx.x;
  const int* bk = buckets + (size_t)br * TLEN;
  int* st = sticker + (size_t)br * TLEN;
  int* ps = pos ? pos + (size_t)br * TLEN : nullptr;

  for (int i = 0; i < 128; ++i) lhist[lane][i] = 0;
  __syncthreads();
  for (int i = 0; i < 64; ++i) lhist[lane][bk[lane * 64 + i]]++;
  __syncthreads();

  int tot0 = 0, tot1 = 0;
  for (int c = 0; c < 64; ++c) {
    int v0 = lhist[c][lane];      lhist[c][lane]      = tot0; tot0 += v0;
    int v1 = lhist[c][lane + 64]; lhist[c][lane + 64] = tot1; tot1 += v1;
  }
  int s0 = tot0;
  for (int off = 1; off < 64; off <<= 1) {
    int u = __shfl_up(s0, off, 64);
    if (lane >= off) s0 += u;
  }
  int total0 = __shfl(s0, 63, 64);
  int s1 = tot1;
  for (int off = 1; off < 64; off <<= 1) {
    int u = __shfl_up(s1, off, 64);
    if (lane >= off) s1 += u;
  }
  starts[lane] = s0 - tot0;
  starts[lane + 64] = s1 - tot1 + total0;
  __syncthreads();

  for (int i = 0; i < 64; ++i) {
    int e = lane * 64 + i;
    int bb = bk[e];
    int c = lhist[lane][bb];
    lhist[lane][bb] = c + 1;
    int sp = starts[bb] + c;
    st[sp] = e;
    if (ps) ps[e] = sp;
  }
}

// ---------------------------------------------------------------------------
// MFMA attention (unchanged from verified r13): swapped QK^T, key-permuted
// sigma tiles, in-register P (bf16 hi only in PV), deferred row-correct invZ.
// ---------------------------------------------------------------------------
__global__ __launch_bounds__(256, 2)
void attn_kernel(const unsigned short* __restrict__ qh, const unsigned short* __restrict__ ql,
                 const unsigned short* __restrict__ kh, const unsigned short* __restrict__ kl,
                 const unsigned short* __restrict__ vh,
                 const int* __restrict__ sticker_q, const int* __restrict__ sticker_k,
                 unsigned short* __restrict__ so_buf, float* __restrict__ slse_buf,
                 int b_off) {
  __shared__ __align__(16) unsigned short Khi[128 * 64];  // 16 KB
  __shared__ __align__(16) unsigned short Klo[128 * 64];  // 16 KB
  __shared__ __align__(16) unsigned short VtS[64 * 128];  // 16 KB, Vt[d][key]

  const int tid = threadIdx.x;
  const int w = tid >> 6;
  const int l = tid & 63;
  const int l15 = l & 15;
  const int qd = l >> 4;
  const int n = blockIdx.x, r = blockIdx.y, bl = blockIdx.z;
  const int b = b_off + bl;
  const size_t brbase = ((size_t)b * NHASH + r) * TLEN;
  const size_t obase  = ((size_t)bl * NHASH + r) * TLEN;
  const int nprev = (n + NBUCK - 1) & (NBUCK - 1);

  // ---- stage K hi/lo: pure short8 copies; granule swizzle g ^ f(row),
  //      f(row) = (row ^ (row>>1)) & 7
  for (int it = 0; it < 4; ++it) {
    int idx = it * 256 + tid;         // 1024 = 128 rows x 8 granules
    int row = idx >> 3, gc = idx & 7;
    int srow = (row < 64) ? (nprev * 64 + row) : (n * 64 + (row - 64));
    int ik = sticker_k[brbase + srow];
    size_t src = ((size_t)bl * TLEN + ik) * DIM + gc * 8;
    int fr = (row ^ (row >> 1)) & 7;
    int o = (row << 6) + ((gc ^ fr) << 3);
    *(short8*)&Khi[o] = *(const short8*)(kh + src);
    *(short8*)&Klo[o] = *(const short8*)(kl + src);
  }
  // ---- stage V transposed, key-major lanes
  for (int it = 0; it < 4; ++it) {
    int idx = it * 256 + tid;         // 1024 = 128 keys x 8 d-groups
    int key = idx & 127, dg = idx >> 7;
    int srow = (key < 64) ? (nprev * 64 + key) : (n * 64 + (key - 64));
    int ik = sticker_k[brbase + srow];
    ushort8 vv = *(const ushort8*)(vh + ((size_t)bl * TLEN + ik) * DIM + dg * 8);
    int kg = key >> 3, kr = key & 7;
#pragma unroll
    for (int e = 0; e < 8; ++e) {
      int d = dg * 8 + e;
      VtS[d * 128 + ((kg ^ (d & 15)) << 3) + kr] = vv[e];
    }
  }

  // ---- Q fragments: direct short8 loads (pre-scaled, pre-split)
  const int torig = sticker_q[brbase + n * 64 + w * 16 + l15];
  short8 Ahi[2], Alo[2];
#pragma unroll
  for (int ks = 0; ks < 2; ++ks) {
    size_t src = ((size_t)bl * TLEN + torig) * DIM + ks * 32 + qd * 8;
    Ahi[ks] = *(const short8*)(qh + src);
    Alo[ks] = *(const short8*)(ql + src);
  }
  __syncthreads();

  // ---- swapped QK^T: S^T tiles, bf16x3. Tile nt row l15 <- key
  //      32*(nt&3) + 4*(nt>>2) + kp, kp = 8*(l15>>2) + (l15&3).
  const int kp = ((l15 >> 2) << 3) + (l15 & 3);
  float4v Sacc[8];
#pragma unroll
  for (int nt = 0; nt < 8; ++nt) {
    float4v z = {0.f, 0.f, 0.f, 0.f};
    Sacc[nt] = z;
    int key = ((nt & 3) << 5) + ((nt >> 2) << 2) + kp;
    int fk = (key ^ (key >> 1)) & 7;
#pragma unroll
    for (int ksd = 0; ksd < 2; ++ksd) {
      int gk = ksd * 4 + qd;
      int o = (key << 6) + ((gk ^ fk) << 3);
      short8 Bh = *(const short8*)&Khi[o];
      short8 Bl = *(const short8*)&Klo[o];
      Sacc[nt] = __builtin_amdgcn_mfma_f32_16x16x32_bf16(Bh, Ahi[ksd], Sacc[nt], 0, 0, 0);
      Sacc[nt] = __builtin_amdgcn_mfma_f32_16x16x32_bf16(Bh, Alo[ksd], Sacc[nt], 0, 0, 0);
      Sacc[nt] = __builtin_amdgcn_mfma_f32_16x16x32_bf16(Bl, Ahi[ksd], Sacc[nt], 0, 0, 0);
    }
  }

  // ---- softmax for qrow = l15: 32 in-register keys per lane + 2 shuffles
  float mA = -INFINITY, mB = -INFINITY;
#pragma unroll
  for (int nt = 0; nt < 8; nt += 2) {
    mA = fmaxf(mA, fmaxf(fmaxf(Sacc[nt][0], Sacc[nt][1]),
                         fmaxf(Sacc[nt][2], Sacc[nt][3])));
    mB = fmaxf(mB, fmaxf(fmaxf(Sacc[nt + 1][0], Sacc[nt + 1][1]),
                         fmaxf(Sacc[nt + 1][2], Sacc[nt + 1][3])));
  }
  float m = fmaxf(mA, mB);
  m = fmaxf(m, __shfl_xor(m, 16, 64));
  m = fmaxf(m, __shfl_xor(m, 32, 64));

  // exp + immediate bf16 pack (P unnormalized; invZ in epilogue). Hi only.
  unsigned hw[8][2];
  float Zp0 = 0.f, Zp1 = 0.f, Zp2 = 0.f, Zp3 = 0.f;
#pragma unroll
  for (int nt = 0; nt < 8; ++nt) {
    float e0 = __expf(Sacc[nt][0] - m);
    float e1 = __expf(Sacc[nt][1] - m);
    float e2 = __expf(Sacc[nt][2] - m);
    float e3 = __expf(Sacc[nt][3] - m);
    Zp0 += e0; Zp1 += e1; Zp2 += e2; Zp3 += e3;
    unsigned h0, h1;
    asm("v_cvt_pk_bf16_f32 %0, %1, %2" : "=v"(h0) : "v"(e0), "v"(e1));
    asm("v_cvt_pk_bf16_f32 %0, %1, %2" : "=v"(h1) : "v"(e2), "v"(e3));
    hw[nt][0] = h0; hw[nt][1] = h1;
  }
  float Z = (Zp0 + Zp1) + (Zp2 + Zp3);
  Z += __shfl_xor(Z, 16, 64);
  Z += __shfl_xor(Z, 32, 64);
  const float invZ = 1.0f / Z;
  if (qd == 0)
    slse_buf[brbase + n * 64 + w * 16 + l15] = m + __logf(Z);

  // ---- Oacc rows are q-rows qd*4+i; pull their invZ via width-16 shfl
  float zr[4];
#pragma unroll
  for (int i = 0; i < 4; ++i) zr[i] = __shfl(invZ, qd * 4 + i, 16);

  // ---- assemble PV A-fragments: fully lane-local thanks to sigma
  short8 PhA[4];
#pragma unroll
  for (int ks = 0; ks < 4; ++ks) {
    union { uint4v u; short8 s; } uh;
    uh.u = (uint4v){hw[ks][0], hw[ks][1], hw[ks + 4][0], hw[ks + 4][1]};
    PhA[ks] = uh.s;
  }

  // ---- PV: O[16 x 64] per wave; A from registers, B from VtS
  float4v Oacc[4];
#pragma unroll
  for (int dt = 0; dt < 4; ++dt) { float4v z = {0.f, 0.f, 0.f, 0.f}; Oacc[dt] = z; }
#pragma unroll
  for (int ks = 0; ks < 4; ++ks) {
#pragma unroll
    for (int dt = 0; dt < 4; ++dt) {
      int vrow = dt * 16 + l15;
      int gv = (ks * 4 + qd) ^ (vrow & 15);
      short8 Bv = *(const short8*)&VtS[vrow * 128 + (gv << 3)];
      Oacc[dt] = __builtin_amdgcn_mfma_f32_16x16x32_bf16(PhA[ks], Bv, Oacc[dt], 0, 0, 0);
    }
  }

  // ---- epilogue: sorted-order bf16 store (row-correct invZ applied here)
#pragma unroll
  for (int dt = 0; dt < 4; ++dt) {
#pragma unroll
    for (int i = 0; i < 4; ++i) {
      int orow = n * 64 + w * 16 + qd * 4 + i;
      so_buf[(obase + orow) * DIM + dt * 16 + l15] = bf16_rne(Oacc[dt][i] * zr[i]);
    }
  }
}

// ---------------------------------------------------------------------------
// Combine the 8 hash rounds (gather via pos_q); so_buf bf16.
// ---------------------------------------------------------------------------
__global__ __launch_bounds__(256)
void combine_kernel(const unsigned short* __restrict__ so_buf,
                    const float* __restrict__ slse_buf,
                    const int* __restrict__ pos_q, float* __restrict__ out, int b_off) {
  const size_t tid = (size_t)blockIdx.x * 256 + threadIdx.x;  // CB*T*8
  const size_t bt = tid >> 3;
  const int g = (int)(tid & 7);
  const size_t bl = bt >> 12;
  const size_t t = bt & 4095;
  const size_t b = b_off + bl;

  int pp[8];
  float l[8];
  float M = -INFINITY;
#pragma unroll
  for (int rr = 0; rr < 8; ++rr) {
    pp[rr] = pos_q[(b * NHASH + rr) * TLEN + t];
    l[rr] = slse_buf[(b * NHASH + rr) * TLEN + pp[rr]];
    M = fmaxf(M, l[rr]);
  }
  float Z = 0.f;
  float w[8];
#pragma unroll
  for (int rr = 0; rr < 8; ++rr) { w[rr] = __expf(l[rr] - M); Z += w[rr]; }
  const float invZ = 1.0f / Z;

  float s[8] = {0.f, 0.f, 0.f, 0.f, 0.f, 0.f, 0.f, 0.f};
#pragma unroll
  for (int rr = 0; rr < 8; ++rr) {
    ushort8 ov = *(const ushort8*)(so_buf +
        ((bl * NHASH + rr) * TLEN + (size_t)pp[rr]) * DIM + g * 8);
#pragma unroll
    for (int j = 0; j < 8; ++j)
      s[j] = fmaf(w[rr], bf16_to_f32(ov[j]), s[j]);
  }
  float* op = out + (b * TLEN + t) * DIM + g * 8;
  float4 o0 = make_float4(s[0] * invZ, s[1] * invZ, s[2] * invZ, s[3] * invZ);
  float4 o1 = make_float4(s[4] * invZ, s[5] * invZ, s[6] * invZ, s[7] * invZ);
  *(float4*)op = o0;
  *(float4*)(op + 4) = o1;
}

// ---------------------------------------------------------------------------
// Workspace layout (adaptive):
//   [0,4) sticker_q  [4,8) sticker_k  [8,12) pos_q  [12,16) slse   (MB)
//   [16MB,+192KB) pjh/pjl/proj_t (prep outputs)
//   [17,21) buckets_q  [21,25) buckets_k            (hash/sort phase)
//   chunk region from 17MB (reused after sorts):
//     so_buf bf16 CB*4MB | qh,ql,kh,kl,vh bf16 CB*0.5MB each
//   total = 17 + 6.5*CB MB;  CB in {32..1} largest fitting (min 23.5 MB).
// ---------------------------------------------------------------------------
extern "C" void kernel_launch(void* const* d_in, const int* in_sizes, int n_in,
                              void* d_out, int out_size, void* d_ws, size_t ws_size,
                              hipStream_t stream) {
  const float* q = (const float*)d_in[0];
  const float* k = (const float*)d_in[1];
  const float* v = (const float*)d_in[2];
  const float* proj = (const float*)d_in[3];
  float* out = (float*)d_out;

  char* ws = (char*)d_ws;
  const size_t MB = (size_t)1 << 20;
  const size_t KB = (size_t)1 << 10;
  int* sticker_q = (int*)(ws + 0 * MB);
  int* sticker_k = (int*)(ws + 4 * MB);
  int* pos_q     = (int*)(ws + 8 * MB);
  float* slse_buf = (float*)(ws + 12 * MB);
  unsigned short* pjh = (unsigned short*)(ws + 16 * MB);
  unsigned short* pjl = (unsigned short*)(ws + 16 * MB + 64 * KB);
  float* proj_t  = (float*)(ws + 16 * MB + 128 * KB);
  int* buckets_q = (int*)(ws + 17 * MB);
  int* buckets_k = (int*)(ws + 21 * MB);

  int CB = 32;
  while (CB > 1 && 17 * MB + (size_t)CB * 13 * MB / 2 > ws_size) CB >>= 1;

  char* chunk = ws + 17 * MB;
  unsigned short* so_buf = (unsigned short*)chunk;
  unsigned short* qh = (unsigned short*)(chunk + (size_t)CB * 4 * MB);
  unsigned short* ql = (unsigned short*)(chunk + (size_t)CB * 9 * MB / 2);
  unsigned short* kh = (unsigned short*)(chunk + (size_t)CB * 5 * MB);
  unsigned short* kl = (unsigned short*)(chunk + (size_t)CB * 11 * MB / 2);
  unsigned short* vh = (unsigned short*)(chunk + (size_t)CB * 6 * MB);

  prep_kernel<<<dim3(NHASH), 256, 0, stream>>>(proj, pjh, pjl, proj_t);
  hash_kernel<<<dim3(TLEN / 64, BATCH, 2), 256, 0, stream>>>(
      q, k, proj_t, pjh, pjl, buckets_q, buckets_k);
  sort_kernel<<<dim3(BATCH * NHASH), 64, 0, stream>>>(buckets_q, sticker_q, pos_q);
  sort_kernel<<<dim3(BATCH * NHASH), 64, 0, stream>>>(buckets_k, sticker_k, nullptr);

  for (int b_off = 0; b_off < BATCH; b_off += CB) {
    convert_kernel<<<dim3(CB * 128, 3), 256, 0, stream>>>(q, k, v, qh, ql, kh, kl, vh, b_off);
    attn_kernel<<<dim3(NBUCK, NHASH, CB), 256, 0, stream>>>(
        qh, ql, kh, kl, vh, sticker_q, sticker_k, so_buf, slse_buf, b_off);
    combine_kernel<<<dim3(CB * TLEN * 8 / 256), 256, 0, stream>>>(
        so_buf, slse_buf, pos_q, out, b_off);
  }
}